// Round 7
// baseline (15803.400 us; speedup 1.0000x reference)
//
// AttentionDecoder on MI355X — round 7: identical to round 5/6 (two GPU-acquire timeouts; never ran)
//
//   pack_kernel : f32->f16 pair layouts (incl. per-member resident layouts GW4/QW4/ALW4/MEM4)
//   keys_kernel : keys = memory @ Wm, *2log2e, plain [b][e][a] f16
//   xg_kernel   : xg[t] = x_t @ Wx_dec[0:400] + b_dec
//   decoder_kernel: 256 wgs = 32 groups x 8 members x 512 thr. Weights VGPR-resident.
//     per step: P1 gates (distributed) -> h; q as K-distributed partials -> sync1 ->
//     gather h + sum q -> P4 scores (keys resident) -> sync2 -> replicated softmax ->
//     ctx (mem resident) -> attn K-partials -> sync3. Alignments buffered in LDS,
//     transposed+written coalesced in epilogue. ATTN written as f16 pairs.
//   gru_kernel x2: as round 4 but f16 I/O; h recurrence f32 in-register.

#include <hip/hip_runtime.h>
#include <hip/hip_fp16.h>
#include <stdint.h>

#define TDEC 200

// ---------- ws layout (bytes) ----------
static constexpr size_t OFF_CNT  = 0;                        // 128 uints (dec:0-31, gru1:32-63, gru2:64-95)
static constexpr size_t OFF_WXX4 = 512;                      // [50][768][4] uint (xg staging weights)
static constexpr size_t OFF_GW4  = OFF_WXX4 + 614400;        // gates resident: 196608 uint
static constexpr size_t OFF_QW4  = OFF_GW4  + 786432;        // 32768 uint
static constexpr size_t OFF_ALW4 = OFF_QW4  + 131072;        // 65536 uint
static constexpr size_t OFF_MEM4 = OFF_ALW4 + 262144;        // 1048576 uint
static constexpr size_t OFF_WM4  = OFF_MEM4 + 4194304;       // [32][256][4] uint (keys_kernel)
static constexpr size_t OFF_WX1P = OFF_WM4  + 131072;        // [128][768] uint
static constexpr size_t OFF_WH1P = OFF_WX1P + 393216;
static constexpr size_t OFF_WX2P = OFF_WH1P + 393216;
static constexpr size_t OFF_WH2P = OFF_WX2P + 393216;
static constexpr size_t OFF_WOUTP= OFF_WH2P + 393216;        // [128][400] uint
static constexpr size_t OFF_KEYS = OFF_WOUTP + 204800;       // __half [32][256][256] plain, *2log2e
static constexpr size_t OFF_XG   = OFF_KEYS + 4194304;       // __half [32][200][768]
static constexpr size_t OFF_ATTN = OFF_XG + 9830400;         // uint(half2) [32][200][128]
static constexpr size_t OFF_HBUF = OFF_ATTN + 3276800;       // float [32][256]
static constexpr size_t OFF_QPART= OFF_HBUF + 32768;         // float [32][8][256]
static constexpr size_t OFF_SCB  = OFF_QPART + 262144;       // float [32][256]
static constexpr size_t OFF_APART= OFF_SCB + 32768;          // float [32][8][256]
static constexpr size_t WS_NEED  = OFF_APART + 262144;       // ~25.8 MB
// aliases (dead regions by GRU time): Y1 in KEYS, Y2 in XG — each uint[32][200][128]
static constexpr size_t OFF_Y1   = OFF_KEYS;
static constexpr size_t OFF_Y2   = OFF_XG;

#define AOFF 2560000   // alignments offset in d_out (floats)

// ---------- helpers ----------
#if __has_builtin(__builtin_amdgcn_exp2f)
#define FEXP2(x) __builtin_amdgcn_exp2f(x)
#else
#define FEXP2(x) exp2f(x)
#endif
#if __has_builtin(__builtin_amdgcn_rcpf)
#define FRCP(x) __builtin_amdgcn_rcpf(x)
#else
#define FRCP(x) (1.0f/(x))
#endif

typedef _Float16 h2t __attribute__((ext_vector_type(2)));

static __device__ __forceinline__ float fdot2u(unsigned a, unsigned b, float c){
  return __builtin_amdgcn_fdot2(__builtin_bit_cast(h2t, a), __builtin_bit_cast(h2t, b), c, false);
}
static __device__ __forceinline__ unsigned pk2(float a, float b){
  auto r = __builtin_amdgcn_cvt_pkrtz(a, b);
  return __builtin_bit_cast(unsigned, r);
}
static __device__ __forceinline__ float lo2(unsigned u){ h2t h = __builtin_bit_cast(h2t,u); return (float)h[0]; }
static __device__ __forceinline__ float hi2(unsigned u){ h2t h = __builtin_bit_cast(h2t,u); return (float)h[1]; }
static __device__ __forceinline__ float sigf(float x){ return FRCP(1.f + FEXP2(x * -1.44269504f)); }
static __device__ __forceinline__ float tanhf_(float x){ return 1.f - 2.f * FRCP(1.f + FEXP2(x * 2.88539008f)); }
#define DOT4(acc, U_, W_) do{ acc = fdot2u((U_).x,(W_).x,acc); acc = fdot2u((U_).y,(W_).y,acc); \
                              acc = fdot2u((U_).z,(W_).z,acc); acc = fdot2u((U_).w,(W_).w,acc);}while(0)
#define AG __HIP_MEMORY_SCOPE_AGENT
static __device__ __forceinline__ void gstoref(float* p, float v){ __hip_atomic_store(p, v, __ATOMIC_RELAXED, AG); }
static __device__ __forceinline__ float gloadf(const float* p){ return __hip_atomic_load(p, __ATOMIC_RELAXED, AG); }
static __device__ __forceinline__ void gstoreu(unsigned* p, unsigned v){ __hip_atomic_store(p, v, __ATOMIC_RELAXED, AG); }
static __device__ __forceinline__ unsigned gloadu(const unsigned* p){ return __hip_atomic_load(p, __ATOMIC_RELAXED, AG); }

// ---------- pack kernel ----------
__global__ __launch_bounds__(256) void pack_kernel(
    const float* Wxd, const float* Whd, const float* Wqm, const float* Walm, const float* Wmm,
    const float* Wx1, const float* Wh1, const float* Wx2, const float* Wh2, const float* Woutm,
    const float* memory, unsigned* ws)
{
  int blk = blockIdx.x, tid = threadIdx.x;
  if (blk < 600){ // WXX4: rows 0..399 of Wx_dec, [kc][768][4]
    unsigned u = blk*256u + tid; int kc = u/3072, r = u%3072, c = r>>2, i = r&3, row = 8*kc+2*i;
    ws[OFF_WXX4/4 + u] = pk2(Wxd[row*768+c], Wxd[(row+1)*768+c]); return; } blk -= 600;
  if (blk < 768){ // GW4: member-resident gate weights (WxA rows 400.. for kp<128, Wh for kp>=128)
    unsigned u = blk*256u + tid;
    int m = u/24576, r = u%24576, j = r/768, r2 = r%768, g = r2>>8, r3 = r2&255, s = r3>>6, i = r3&63;
    int kp = s*64 + i, col = g*256 + m*32 + j;
    float v0, v1;
    if (kp < 128){ int row = 400 + 2*kp; v0 = Wxd[row*768+col]; v1 = Wxd[(row+1)*768+col]; }
    else         { int row = 2*(kp-128); v0 = Whd[row*768+col]; v1 = Whd[(row+1)*768+col]; }
    ws[OFF_GW4/4 + u] = pk2(v0, v1); return; } blk -= 768;
  if (blk < 128){ // QW4: Wq K-rows per member, j-pairs
    unsigned u = blk*256u + tid;
    int m = u>>12, a = (u>>4)&255, s2 = (u>>3)&1, i = u&7;
    int j0 = m*32 + (s2*8+i)*2;
    ws[OFF_QW4/4 + u] = pk2(Wqm[j0*256+a], Wqm[(j0+1)*256+a]); return; } blk -= 128;
  if (blk < 256){ // ALW4: Wal K-rows (h-slice s3=0, ctx-slice s3=1)
    unsigned u = blk*256u + tid;
    int m = u>>13, c = (u>>5)&255, s3 = (u>>4)&1, i = u&15;
    int row0 = (s3 ? 256 + m*32 : m*32) + 2*i;
    ws[OFF_ALW4/4 + u] = pk2(Walm[row0*256+c], Walm[(row0+1)*256+c]); return; } blk -= 256;
  if (blk < 4096){ // MEM4: memory e-pairs x member d-slice
    unsigned u = blk*256u + tid;
    int b = u>>15, m = (u>>12)&7, d = (u>>7)&31, ec = (u>>3)&15, i = u&7;
    int e0 = (ec*8+i)*2, col = m*32 + d;
    ws[OFF_MEM4/4 + u] = pk2(memory[((size_t)(b*256+e0))*256+col],
                             memory[((size_t)(b*256+e0+1))*256+col]); return; } blk -= 4096;
  if (blk < 128){ // WM4 (keys_kernel)
    unsigned u = blk*256u + tid; int kc = u>>10, c = (u>>2)&255, i = u&3, row = 8*kc+2*i;
    ws[OFF_WM4/4 + u] = pk2(Wmm[row*256+c], Wmm[(row+1)*256+c]); return; } blk -= 128;
  if (blk < 384){ unsigned u = blk*256u + tid; int k2 = u/768, c = u%768;
    ws[OFF_WX1P/4 + u] = pk2(Wx1[2*k2*768+c], Wx1[(2*k2+1)*768+c]); return; } blk -= 384;
  if (blk < 384){ unsigned u = blk*256u + tid; int k2 = u/768, c = u%768;
    ws[OFF_WH1P/4 + u] = pk2(Wh1[2*k2*768+c], Wh1[(2*k2+1)*768+c]); return; } blk -= 384;
  if (blk < 384){ unsigned u = blk*256u + tid; int k2 = u/768, c = u%768;
    ws[OFF_WX2P/4 + u] = pk2(Wx2[2*k2*768+c], Wx2[(2*k2+1)*768+c]); return; } blk -= 384;
  if (blk < 384){ unsigned u = blk*256u + tid; int k2 = u/768, c = u%768;
    ws[OFF_WH2P/4 + u] = pk2(Wh2[2*k2*768+c], Wh2[(2*k2+1)*768+c]); return; } blk -= 384;
  { // WOUTP (200 blocks)
    unsigned u = blk*256u + tid; int k2 = u/400, c = u%400;
    ws[OFF_WOUTP/4 + u] = pk2(Woutm[2*k2*400+c], Woutm[(2*k2+1)*400+c]);
  }
}

// ---------- keys kernel: keysH[b][e][a] = (mem[b]@Wm)[e][a]*2log2e ----------
__global__ __launch_bounds__(256) void keys_kernel(const float* memory, const unsigned* wm4, __half* keysH)
{
  int tid = threadIdx.x;
  int b = blockIdx.x >> 3, et = blockIdx.x & 7, e0 = et*32, a = tid;
  __shared__ __align__(16) unsigned a2[32][4];
  float acc[32];
  #pragma unroll
  for (int e=0;e<32;e++) acc[e]=0.f;
  for (int kc=0;kc<32;kc++){
    if (tid < 128){
      int e = tid>>2, i = tid&3;
      const float* mr = memory + (size_t)(b*256 + e0+e)*256 + 8*kc + 2*i;
      a2[e][i] = pk2(mr[0], mr[1]);
    }
    __syncthreads();
    uint4 wv = ((const uint4*)wm4)[kc*256 + a];
    #pragma unroll
    for (int e=0;e<32;e++){ uint4 uv = *((const uint4*)a2[e]); DOT4(acc[e], uv, wv); }
    __syncthreads();
  }
  __half* base = keysH + (size_t)(b*256 + e0)*256;
  #pragma unroll
  for (int e=0;e<32;e++) base[(size_t)e*256 + a] = __float2half(acc[e]*2.88539008f);
}

// ---------- xg kernel ----------
__global__ __launch_bounds__(768) void xg_kernel(const float* inputs, const float* bdec,
                                                 const unsigned* wxx4, __half* xg)
{
  int tid = threadIdx.x;
  int b = blockIdx.x >> 3, t0 = (blockIdx.x & 7)*25;
  __shared__ __align__(16) unsigned xp[25][200];
  for (int idx = tid; idx < 5000; idx += 768){
    int tt = idx/200, kk = idx%200;
    float2 v = ((const float2*)(inputs + (size_t)(b*200 + t0+tt)*400))[kk];
    xp[tt][kk] = pk2(v.x, v.y);
  }
  __syncthreads();
  int c = tid;
  float bd = bdec[c];
  float acc[25];
  #pragma unroll
  for (int tt=0;tt<25;tt++) acc[tt]=bd;
  for (int kc=0;kc<50;kc++){
    uint4 wv = ((const uint4*)wxx4)[kc*768 + c];
    #pragma unroll
    for (int tt=0;tt<25;tt++){ uint4 xv = ((const uint4*)xp[tt])[kc]; DOT4(acc[tt], xv, wv); }
  }
  __half* xr = xg + (size_t)b*153600;
  #pragma unroll
  for (int tt=0;tt<25;tt++) xr[(size_t)(t0+tt)*768 + c] = __float2half(acc[tt]);
}

// ---------- decoder: 256 wgs = 32 groups x 8 members, 512 thr ----------
__global__ __launch_bounds__(512, 2) void decoder_kernel(
    const float* va, const unsigned* gw4, const unsigned* qw4, const unsigned* alw4,
    const unsigned* mem4, const unsigned* keysU, const __half* xgAll,
    unsigned* attn2, float* out, unsigned* cnt,
    float* hbuf, float* qpart, float* scbuf, float* apart)
{
  const int tid = threadIdx.x;
  const int b = blockIdx.x & 31, m = blockIdx.x >> 5;

  // ---- resident weights ----
  unsigned wgt[64];
  { int j = tid>>4, g=(tid>>2)&3, s=tid&3;
    if (g<3){
      int base = (((m*32+j)*3+g)*4+s)*64;
      #pragma unroll
      for (int i=0;i<64;i++) wgt[i] = gw4[base+i];
    } else {
      #pragma unroll
      for (int i=0;i<64;i++) wgt[i] = 0u;
    } }
  unsigned wq[8];
  { int base = ((m*256 + (tid>>1))*2 + (tid&1))*8;
    #pragma unroll
    for (int i=0;i<8;i++) wq[i] = qw4[base+i]; }
  unsigned kk[8];
  { int base = ((b*256 + m*32 + (tid>>4))*128) + (tid&15)*8;
    #pragma unroll
    for (int i=0;i<8;i++) kk[i] = keysU[base+i]; }
  unsigned mmr[8];
  { int base = (((b*8+m)*32 + (tid>>4))*16 + (tid&15))*8;
    #pragma unroll
    for (int i=0;i<8;i++) mmr[i] = mem4[base+i]; }
  unsigned aw[16];
  { int base = ((m*256 + (tid>>1))*2 + (tid&1))*16;
    #pragma unroll
    for (int i=0;i<16;i++) aw[i] = alw4[base+i]; }

  __shared__ float vf[256], qf[256], alf[256], aff[256];
  __shared__ float gz[32], gr[32], gnx[32], gnh[32], hff[32], cfs[32], red[16];
  __shared__ __align__(16) unsigned attnp[128], h2s[128], al2[128], hop[16], ctxp[16];
  __shared__ float trp[200][33];
  __shared__ float VsumS;

  const __half* xgb = xgAll + (size_t)b*153600;
  unsigned* attn2b = attn2 + (size_t)b*25600;
  float* hbufb = hbuf + b*256;
  float* qpb = qpart + b*2048;
  float* scb = scbuf + b*256;
  float* apb = apart + b*2048;
  unsigned* cg = cnt + b;

  if (tid<256) vf[tid]=va[tid];
  if (tid<128){ attnp[tid]=0u; h2s[tid]=0u; }
  __syncthreads();
  { float vs = (tid<256)? vf[tid] : 0.f;
    #pragma unroll
    for (int off=32; off; off>>=1) vs += __shfl_xor(vs, off);
    if ((tid&63)==0) red[tid>>6]=vs;
    __syncthreads();
    if (tid==0){ float s2=0; for (int i=0;i<8;i++) s2+=red[i]; VsumS=s2; }
    __syncthreads(); }

  float h_own = 0.f;
  unsigned tgt = 0;

  for (int t=0; t<TDEC; t++){
    // recon attn(t-1) from apart partials
    if (t>0){
      if (tid<256){
        float s2=0;
        #pragma unroll
        for (int mm2=0;mm2<8;mm2++) s2 += gloadf(apb + mm2*256 + tid);
        aff[tid]=s2;
      }
      __syncthreads();
      if (tid<128){
        unsigned u = pk2(aff[2*tid], aff[2*tid+1]);
        attnp[tid]=u;
        if (m==0) gstoreu(attn2b + (t-1)*128 + tid, u);
      }
      __syncthreads();
    }
    // P1 gates
    { int j=tid>>4, g=(tid>>2)&3, s=tid&3;
      if (g<3){
        float acc=0.f;
        const unsigned* opb = (s&2)? h2s : attnp;
        int off = (s&1)*64;
        #pragma unroll
        for (int i=0;i<64;i++) acc = fdot2u(opb[off+i], wgt[i], acc);
        float o1 = __shfl_xor(acc,1);
        acc += o1;
        if (g<2){
          acc += __shfl_xor(acc,2);
          if (s==0){
            float xgv = __half2float(xgb[(size_t)t*768 + g*256 + m*32 + j]);
            if (g==0) gz[j] = acc + xgv; else gr[j] = acc + xgv;
          }
        } else {
          if (s==0){ float xgv = __half2float(xgb[(size_t)t*768 + 512 + m*32 + j]); gnx[j] = acc + xgv; }
          if (s==2) gnh[j] = acc;
        }
      } }
    __syncthreads();
    // P2 h update
    if (tid<32){
      int j=tid;
      float z = sigf(gz[j]);
      float r = sigf(gr[j]);
      float n = tanhf_(gnx[j] + r*gnh[j]);
      float hn = z*h_own + (1.f-z)*n;
      h_own = hn;
      hff[j] = hn;
      gstoref(hbufb + m*32 + j, hn);
    }
    __syncthreads();
    if (tid<16) hop[tid] = pk2(hff[2*tid], hff[2*tid+1]);
    __syncthreads();
    // P3a q partial (Wq K-rows of own h-slice)
    { int a=tid>>1, s2=tid&1;
      float acc=0.f;
      #pragma unroll
      for (int i=0;i<8;i++) acc = fdot2u(hop[s2*8+i], wq[i], acc);
      acc += __shfl_xor(acc,1);
      if (s2==0) gstoref(qpb + m*256 + a, acc);
    }
    __syncthreads();
    // sync1
    tgt += 8;
    if (tid==0){
      __threadfence();
      __hip_atomic_fetch_add(cg, 1u, __ATOMIC_RELEASE, AG);
      while (__hip_atomic_load(cg, __ATOMIC_ACQUIRE, AG) < tgt) __builtin_amdgcn_s_sleep(1);
    }
    __syncthreads();
    // gather h (thr 0..255) and q (thr 256..511)
    if (tid<256) aff[tid] = gloadf(hbufb + tid);
    else { int a = tid-256; float s2=0;
      #pragma unroll
      for (int mm2=0;mm2<8;mm2++) s2 += gloadf(qpb + mm2*256 + a);
      qf[a] = s2*2.88539008f; }
    __syncthreads();
    if (tid<128) h2s[tid] = pk2(aff[2*tid], aff[2*tid+1]);
    __syncthreads();
    // P4 scores (keys resident)
    { int e=tid>>4, at=tid&15;
      float acc=0.f;
      #pragma unroll
      for (int i=0;i<8;i++){
        int a0 = at*16 + 2*i;
        float w0 = FEXP2(lo2(kk[i]) + qf[a0]);   acc = fmaf(vf[a0],   FRCP(1.f+w0), acc);
        float w1 = FEXP2(hi2(kk[i]) + qf[a0+1]); acc = fmaf(vf[a0+1], FRCP(1.f+w1), acc);
      }
      acc += __shfl_xor(acc,1); acc += __shfl_xor(acc,2);
      acc += __shfl_xor(acc,4); acc += __shfl_xor(acc,8);
      if (at==0) gstoref(scb + m*32 + e, VsumS - 2.f*acc);
    }
    __syncthreads();
    // sync2
    tgt += 8;
    if (tid==0){
      __threadfence();
      __hip_atomic_fetch_add(cg, 1u, __ATOMIC_RELEASE, AG);
      while (__hip_atomic_load(cg, __ATOMIC_ACQUIRE, AG) < tgt) __builtin_amdgcn_s_sleep(1);
    }
    __syncthreads();
    // replicated softmax
    { float x = (tid<256)? gloadf(scb + tid) : -3.0e38f;
      float mx = x;
      #pragma unroll
      for (int off=32; off; off>>=1) mx = fmaxf(mx, __shfl_xor(mx, off));
      if ((tid&63)==0) red[tid>>6] = mx;
      __syncthreads();
      float gm = fmaxf(fmaxf(fmaxf(red[0],red[1]),fmaxf(red[2],red[3])),
                       fmaxf(fmaxf(red[4],red[5]),fmaxf(red[6],red[7])));
      float p = (tid<256)? FEXP2((x-gm)*1.44269504f) : 0.f;
      float ss = p;
      #pragma unroll
      for (int off=32; off; off>>=1) ss += __shfl_xor(ss, off);
      if ((tid&63)==0) red[8+(tid>>6)] = ss;
      __syncthreads();
      float S = (red[8]+red[9])+(red[10]+red[11])+(red[12]+red[13])+(red[14]+red[15]);
      if (tid<256) alf[tid] = p * FRCP(S);
    }
    __syncthreads();
    if (tid<128) al2[tid] = pk2(alf[2*tid], alf[2*tid+1]);
    if (tid<32) trp[t][tid] = alf[m*32+tid];
    __syncthreads();
    // P6 ctx (mem resident)
    { int d=tid>>4, ec=tid&15;
      float acc=0.f;
      #pragma unroll
      for (int i=0;i<8;i++) acc = fdot2u(al2[ec*8+i], mmr[i], acc);
      acc += __shfl_xor(acc,1); acc += __shfl_xor(acc,2);
      acc += __shfl_xor(acc,4); acc += __shfl_xor(acc,8);
      if (ec==0) cfs[d]=acc;
    }
    __syncthreads();
    if (tid<16) ctxp[tid] = pk2(cfs[2*tid], cfs[2*tid+1]);
    __syncthreads();
    // P7 attn K-partials
    { int s3=tid&1;
      const unsigned* ob = s3? ctxp : hop;
      float acc=0.f;
      #pragma unroll
      for (int i=0;i<16;i++) acc = fdot2u(ob[i], aw[i], acc);
      acc += __shfl_xor(acc,1);
      if (s3==0) gstoref(apb + m*256 + (tid>>1), acc);
    }
    __syncthreads();
    // sync3
    tgt += 8;
    if (tid==0){
      __threadfence();
      __hip_atomic_fetch_add(cg, 1u, __ATOMIC_RELEASE, AG);
      while (__hip_atomic_load(cg, __ATOMIC_ACQUIRE, AG) < tgt) __builtin_amdgcn_s_sleep(1);
    }
    __syncthreads();
  }

  // epilogue: final attn(199)
  if (tid<256){
    float s2=0;
    #pragma unroll
    for (int mm2=0;mm2<8;mm2++) s2 += gloadf(apb + mm2*256 + tid);
    aff[tid]=s2;
  }
  __syncthreads();
  if (tid<128 && m==0) gstoreu(attn2b + 199*128 + tid, pk2(aff[2*tid], aff[2*tid+1]));
  // alignments transpose: member m writes its e-slice coalesced along t
  for (int e=0;e<32;e++){
    for (int tt=tid; tt<200; tt+=512)
      out[AOFF + (size_t)b*51200 + (size_t)(m*32+e)*200 + tt] = trp[tt][e];
  }
}

// ---------- GRU kernel (f16 I/O): 32 groups x 8 members ----------
__global__ __launch_bounds__(256) void gru_kernel(
    const unsigned* xa2, const unsigned* xb2,
    const unsigned* Wxp, const unsigned* Whp, const float* bias,
    unsigned* ye2, unsigned* cnt,
    const unsigned* Woutp, const float* bout, float* melout)
{
  const int tid = threadIdx.x;
  const int b = blockIdx.x & 31, m = blockIdx.x >> 5;
  const int c = (tid<192)? tid%96 : 0, s = (tid<192)? tid/96 : 0;
  const int col = (c>>5)*256 + m*32 + (c&31);

  unsigned wx[64], wh[64];
  if (tid<192){
    #pragma unroll
    for (int i=0;i<64;i++){ wx[i] = Wxp[(size_t)(s*64+i)*768 + col]; wh[i] = Whp[(size_t)(s*64+i)*768 + col]; }
  }
  unsigned wo[32];
  if (Woutp && tid<200){
    int mc = m*50 + tid%50, so = tid/50;
    #pragma unroll
    for (int i=0;i<32;i++) wo[i] = Woutp[(size_t)(so*32+i)*400 + mc];
  }
  __shared__ float bsl[96], bml[50];
  __shared__ __align__(16) float o1f[256];
  __shared__ __align__(16) unsigned h2[128], in2[128];
  __shared__ float pax[192], pah[192], pm[200];
  if (tid<96) bsl[tid] = bias[(tid>>5)*256 + m*32 + (tid&31)];
  if (Woutp && tid<50) bml[tid] = bout[m*50+tid];
  if (tid<128) h2[tid]=0u;
  __syncthreads();

  const unsigned* xa = xa2 + (size_t)b*25600;
  const unsigned* xb = xb2 ? xb2 + (size_t)b*25600 : nullptr;
  unsigned* ye = ye2 + (size_t)b*25600;
  unsigned* cg = cnt + b;
  float h_own = 0.f;

  for (int t=0;t<TDEC;t++){
    if (tid<128){
      unsigned ua = xa[t*128+tid];
      if (xb){
        unsigned ub = xb[t*128+tid];
        float x0 = lo2(ua)+lo2(ub), x1 = hi2(ua)+hi2(ub);
        o1f[2*tid]=x0; o1f[2*tid+1]=x1;
        in2[tid]=pk2(x0,x1);
      } else in2[tid]=ua;
    }
    __syncthreads();
    if (tid<192){
      float ax=0.f, ah=0.f;
      #pragma unroll
      for (int i4=0;i4<16;i4++){
        uint4 uv = ((const uint4*)in2)[s*16+i4];
        ax = fdot2u(uv.x, wx[i4*4+0], ax); ax = fdot2u(uv.y, wx[i4*4+1], ax);
        ax = fdot2u(uv.z, wx[i4*4+2], ax); ax = fdot2u(uv.w, wx[i4*4+3], ax);
        uint4 vv = ((const uint4*)h2)[s*16+i4];
        ah = fdot2u(vv.x, wh[i4*4+0], ah); ah = fdot2u(vv.y, wh[i4*4+1], ah);
        ah = fdot2u(vv.z, wh[i4*4+2], ah); ah = fdot2u(vv.w, wh[i4*4+3], ah);
      }
      pax[tid]=ax; pah[tid]=ah;
    }
    __syncthreads();
    if (tid<32){
      int j=tid;
      float z = sigf(pax[j]    + pax[96+j]  + bsl[j]    + pah[j]    + pah[96+j]);
      float r = sigf(pax[32+j] + pax[128+j] + bsl[32+j] + pah[32+j] + pah[128+j]);
      float n = tanhf_(pax[64+j] + pax[160+j] + bsl[64+j] + r*(pah[64+j] + pah[160+j]));
      float hn = z*h_own + (1.f-z)*n;
      h_own = hn;
      float hp = __shfl_xor(hn, 1);
      if ((tid&1)==0) gstoreu(ye + t*128 + m*16 + (tid>>1), pk2(hn, hp));
    }
    __syncthreads();
    if (tid==0){
      __threadfence();
      __hip_atomic_fetch_add(cg, 1u, __ATOMIC_RELEASE, AG);
      unsigned tgt2 = 8u*(t+1);
      while (__hip_atomic_load(cg, __ATOMIC_ACQUIRE, AG) < tgt2) __builtin_amdgcn_s_sleep(1);
    }
    __syncthreads();
    if (tid<128) h2[tid] = gloadu(ye + t*128 + tid);
    __syncthreads();
    if (Woutp){
      if (tid<128) in2[tid] = pk2(o1f[2*tid]+lo2(h2[tid]), o1f[2*tid+1]+hi2(h2[tid]));
      __syncthreads();
      if (tid<200){
        int so = tid/50;
        float acc=0.f;
        #pragma unroll
        for (int i4=0;i4<8;i4++){
          uint4 uv = ((const uint4*)in2)[so*8+i4];
          acc = fdot2u(uv.x, wo[i4*4+0], acc); acc = fdot2u(uv.y, wo[i4*4+1], acc);
          acc = fdot2u(uv.z, wo[i4*4+2], acc); acc = fdot2u(uv.w, wo[i4*4+3], acc);
        }
        pm[tid]=acc;
      }
      __syncthreads();
      if (tid<50){
        float mel = pm[tid]+pm[50+tid]+pm[100+tid]+pm[150+tid]+bml[tid];
        melout[(size_t)b*80000 + (size_t)t*400 + m*50 + tid] = mel;
      }
      __syncthreads();
    }
  }
}

// ---------- launch ----------
extern "C" void kernel_launch(void* const* d_in, const int* in_sizes, int n_in,
                              void* d_out, int out_size, void* d_ws, size_t ws_size,
                              hipStream_t stream) {
  if (ws_size < WS_NEED) return;
  const float* inputs = (const float*)d_in[0];
  const float* memory = (const float*)d_in[1];
  const float* Wq  = (const float*)d_in[2];
  const float* Wm  = (const float*)d_in[3];
  const float* va  = (const float*)d_in[4];
  const float* Wal = (const float*)d_in[5];
  const float* Wxd = (const float*)d_in[6];
  const float* Whd = (const float*)d_in[7];
  const float* bdec= (const float*)d_in[8];
  const float* Wx1 = (const float*)d_in[9];
  const float* Wh1 = (const float*)d_in[10];
  const float* b1  = (const float*)d_in[11];
  const float* Wx2 = (const float*)d_in[12];
  const float* Wh2 = (const float*)d_in[13];
  const float* b2  = (const float*)d_in[14];
  const float* Wout= (const float*)d_in[15];
  const float* bout= (const float*)d_in[16];
  float* out = (float*)d_out;

  char* wsb = (char*)d_ws;
  unsigned* wsu = (unsigned*)d_ws;
  const unsigned* WXX4 = (const unsigned*)(wsb + OFF_WXX4);
  const unsigned* GW4  = (const unsigned*)(wsb + OFF_GW4);
  const unsigned* QW4  = (const unsigned*)(wsb + OFF_QW4);
  const unsigned* ALW4 = (const unsigned*)(wsb + OFF_ALW4);
  const unsigned* MEM4 = (const unsigned*)(wsb + OFF_MEM4);
  const unsigned* WM4  = (const unsigned*)(wsb + OFF_WM4);
  const unsigned* WX1P = (const unsigned*)(wsb + OFF_WX1P);
  const unsigned* WH1P = (const unsigned*)(wsb + OFF_WH1P);
  const unsigned* WX2P = (const unsigned*)(wsb + OFF_WX2P);
  const unsigned* WH2P = (const unsigned*)(wsb + OFF_WH2P);
  const unsigned* WOUTP= (const unsigned*)(wsb + OFF_WOUTP);
  __half* KEYS = (__half*)(wsb + OFF_KEYS);
  __half* XG   = (__half*)(wsb + OFF_XG);
  unsigned* ATTN2 = (unsigned*)(wsb + OFF_ATTN);
  float* HBUF = (float*)(wsb + OFF_HBUF);
  float* QPART= (float*)(wsb + OFF_QPART);
  float* SCB  = (float*)(wsb + OFF_SCB);
  float* APART= (float*)(wsb + OFF_APART);
  unsigned* Y1u = (unsigned*)(wsb + OFF_Y1);
  unsigned* Y2u = (unsigned*)(wsb + OFF_Y2);
  unsigned* CNT = (unsigned*)wsb;

  (void)hipMemsetAsync(d_ws, 0, 512, stream);
  pack_kernel<<<7712, 256, 0, stream>>>(Wxd, Whd, Wq, Wal, Wm, Wx1, Wh1, Wx2, Wh2, Wout, memory, wsu);
  keys_kernel<<<256, 256, 0, stream>>>(memory, WM4, KEYS);
  xg_kernel<<<256, 768, 0, stream>>>(inputs, bdec, WXX4, XG);
  decoder_kernel<<<256, 512, 0, stream>>>(va, GW4, QW4, ALW4, MEM4, (const unsigned*)KEYS, XG,
                                          ATTN2, out, CNT, HBUF, QPART, SCB, APART);
  gru_kernel<<<256, 256, 0, stream>>>(ATTN2, nullptr, WX1P, WH1P, b1, Y1u, CNT+32, nullptr, nullptr, nullptr);
  gru_kernel<<<256, 256, 0, stream>>>(ATTN2, Y1u,     WX2P, WH2P, b2, Y2u, CNT+64, WOUTP, bout, out);
}

// Round 8
// 8952.026 us; speedup vs baseline: 1.7653x; 1.7653x over previous
//
// AttentionDecoder on MI355X — round 8: pad group-sync counters to 256B/group (fix false sharing)
// (R7 post-mortem: 32 counters in 128B -> every sync serialized globally at ~16us; decoder 9.8ms
//  was ~100% sync. Single change this round: each group counter gets its own cache line.)

#include <hip/hip_runtime.h>
#include <hip/hip_fp16.h>
#include <stdint.h>

#define TDEC 200

// ---------- ws layout (bytes) ----------
static constexpr size_t OFF_CNT  = 0;                        // 3 x 32 x 256B padded counters (24576 B)
static constexpr size_t OFF_WXX4 = 24576;                    // [50][768][4] uint (xg staging weights)
static constexpr size_t OFF_GW4  = OFF_WXX4 + 614400;        // gates resident: 196608 uint
static constexpr size_t OFF_QW4  = OFF_GW4  + 786432;        // 32768 uint
static constexpr size_t OFF_ALW4 = OFF_QW4  + 131072;        // 65536 uint
static constexpr size_t OFF_MEM4 = OFF_ALW4 + 262144;        // 1048576 uint
static constexpr size_t OFF_WM4  = OFF_MEM4 + 4194304;       // [32][256][4] uint (keys_kernel)
static constexpr size_t OFF_WX1P = OFF_WM4  + 131072;        // [128][768] uint
static constexpr size_t OFF_WH1P = OFF_WX1P + 393216;
static constexpr size_t OFF_WX2P = OFF_WH1P + 393216;
static constexpr size_t OFF_WH2P = OFF_WX2P + 393216;
static constexpr size_t OFF_WOUTP= OFF_WH2P + 393216;        // [128][400] uint
static constexpr size_t OFF_KEYS = OFF_WOUTP + 204800;       // __half [32][256][256] plain, *2log2e
static constexpr size_t OFF_XG   = OFF_KEYS + 4194304;       // __half [32][200][768]
static constexpr size_t OFF_ATTN = OFF_XG + 9830400;         // uint(half2) [32][200][128]
static constexpr size_t OFF_HBUF = OFF_ATTN + 3276800;       // float [32][256]
static constexpr size_t OFF_QPART= OFF_HBUF + 32768;         // float [32][8][256]
static constexpr size_t OFF_SCB  = OFF_QPART + 262144;       // float [32][256]
static constexpr size_t OFF_APART= OFF_SCB + 32768;          // float [32][8][256]
static constexpr size_t WS_NEED  = OFF_APART + 262144;       // ~24.6 MiB
// aliases (dead regions by GRU time): Y1 in KEYS, Y2 in XG — each uint[32][200][128]
static constexpr size_t OFF_Y1   = OFF_KEYS;
static constexpr size_t OFF_Y2   = OFF_XG;

#define AOFF 2560000   // alignments offset in d_out (floats)

// ---------- helpers ----------
#if __has_builtin(__builtin_amdgcn_exp2f)
#define FEXP2(x) __builtin_amdgcn_exp2f(x)
#else
#define FEXP2(x) exp2f(x)
#endif
#if __has_builtin(__builtin_amdgcn_rcpf)
#define FRCP(x) __builtin_amdgcn_rcpf(x)
#else
#define FRCP(x) (1.0f/(x))
#endif

typedef _Float16 h2t __attribute__((ext_vector_type(2)));

static __device__ __forceinline__ float fdot2u(unsigned a, unsigned b, float c){
  return __builtin_amdgcn_fdot2(__builtin_bit_cast(h2t, a), __builtin_bit_cast(h2t, b), c, false);
}
static __device__ __forceinline__ unsigned pk2(float a, float b){
  auto r = __builtin_amdgcn_cvt_pkrtz(a, b);
  return __builtin_bit_cast(unsigned, r);
}
static __device__ __forceinline__ float lo2(unsigned u){ h2t h = __builtin_bit_cast(h2t,u); return (float)h[0]; }
static __device__ __forceinline__ float hi2(unsigned u){ h2t h = __builtin_bit_cast(h2t,u); return (float)h[1]; }
static __device__ __forceinline__ float sigf(float x){ return FRCP(1.f + FEXP2(x * -1.44269504f)); }
static __device__ __forceinline__ float tanhf_(float x){ return 1.f - 2.f * FRCP(1.f + FEXP2(x * 2.88539008f)); }
#define DOT4(acc, U_, W_) do{ acc = fdot2u((U_).x,(W_).x,acc); acc = fdot2u((U_).y,(W_).y,acc); \
                              acc = fdot2u((U_).z,(W_).z,acc); acc = fdot2u((U_).w,(W_).w,acc);}while(0)
#define AG __HIP_MEMORY_SCOPE_AGENT
static __device__ __forceinline__ void gstoref(float* p, float v){ __hip_atomic_store(p, v, __ATOMIC_RELAXED, AG); }
static __device__ __forceinline__ float gloadf(const float* p){ return __hip_atomic_load(p, __ATOMIC_RELAXED, AG); }
static __device__ __forceinline__ void gstoreu(unsigned* p, unsigned v){ __hip_atomic_store(p, v, __ATOMIC_RELAXED, AG); }
static __device__ __forceinline__ unsigned gloadu(const unsigned* p){ return __hip_atomic_load(p, __ATOMIC_RELAXED, AG); }

// ---------- pack kernel ----------
__global__ __launch_bounds__(256) void pack_kernel(
    const float* Wxd, const float* Whd, const float* Wqm, const float* Walm, const float* Wmm,
    const float* Wx1, const float* Wh1, const float* Wx2, const float* Wh2, const float* Woutm,
    const float* memory, unsigned* ws)
{
  int blk = blockIdx.x, tid = threadIdx.x;
  if (blk < 600){ // WXX4: rows 0..399 of Wx_dec, [kc][768][4]
    unsigned u = blk*256u + tid; int kc = u/3072, r = u%3072, c = r>>2, i = r&3, row = 8*kc+2*i;
    ws[OFF_WXX4/4 + u] = pk2(Wxd[row*768+c], Wxd[(row+1)*768+c]); return; } blk -= 600;
  if (blk < 768){ // GW4: member-resident gate weights (WxA rows 400.. for kp<128, Wh for kp>=128)
    unsigned u = blk*256u + tid;
    int m = u/24576, r = u%24576, j = r/768, r2 = r%768, g = r2>>8, r3 = r2&255, s = r3>>6, i = r3&63;
    int kp = s*64 + i, col = g*256 + m*32 + j;
    float v0, v1;
    if (kp < 128){ int row = 400 + 2*kp; v0 = Wxd[row*768+col]; v1 = Wxd[(row+1)*768+col]; }
    else         { int row = 2*(kp-128); v0 = Whd[row*768+col]; v1 = Whd[(row+1)*768+col]; }
    ws[OFF_GW4/4 + u] = pk2(v0, v1); return; } blk -= 768;
  if (blk < 128){ // QW4: Wq K-rows per member, j-pairs
    unsigned u = blk*256u + tid;
    int m = u>>12, a = (u>>4)&255, s2 = (u>>3)&1, i = u&7;
    int j0 = m*32 + (s2*8+i)*2;
    ws[OFF_QW4/4 + u] = pk2(Wqm[j0*256+a], Wqm[(j0+1)*256+a]); return; } blk -= 128;
  if (blk < 256){ // ALW4: Wal K-rows (h-slice s3=0, ctx-slice s3=1)
    unsigned u = blk*256u + tid;
    int m = u>>13, c = (u>>5)&255, s3 = (u>>4)&1, i = u&15;
    int row0 = (s3 ? 256 + m*32 : m*32) + 2*i;
    ws[OFF_ALW4/4 + u] = pk2(Walm[row0*256+c], Walm[(row0+1)*256+c]); return; } blk -= 256;
  if (blk < 4096){ // MEM4: memory e-pairs x member d-slice
    unsigned u = blk*256u + tid;
    int b = u>>15, m = (u>>12)&7, d = (u>>7)&31, ec = (u>>3)&15, i = u&7;
    int e0 = (ec*8+i)*2, col = m*32 + d;
    ws[OFF_MEM4/4 + u] = pk2(memory[((size_t)(b*256+e0))*256+col],
                             memory[((size_t)(b*256+e0+1))*256+col]); return; } blk -= 4096;
  if (blk < 128){ // WM4 (keys_kernel)
    unsigned u = blk*256u + tid; int kc = u>>10, c = (u>>2)&255, i = u&3, row = 8*kc+2*i;
    ws[OFF_WM4/4 + u] = pk2(Wmm[row*256+c], Wmm[(row+1)*256+c]); return; } blk -= 128;
  if (blk < 384){ unsigned u = blk*256u + tid; int k2 = u/768, c = u%768;
    ws[OFF_WX1P/4 + u] = pk2(Wx1[2*k2*768+c], Wx1[(2*k2+1)*768+c]); return; } blk -= 384;
  if (blk < 384){ unsigned u = blk*256u + tid; int k2 = u/768, c = u%768;
    ws[OFF_WH1P/4 + u] = pk2(Wh1[2*k2*768+c], Wh1[(2*k2+1)*768+c]); return; } blk -= 384;
  if (blk < 384){ unsigned u = blk*256u + tid; int k2 = u/768, c = u%768;
    ws[OFF_WX2P/4 + u] = pk2(Wx2[2*k2*768+c], Wx2[(2*k2+1)*768+c]); return; } blk -= 384;
  if (blk < 384){ unsigned u = blk*256u + tid; int k2 = u/768, c = u%768;
    ws[OFF_WH2P/4 + u] = pk2(Wh2[2*k2*768+c], Wh2[(2*k2+1)*768+c]); return; } blk -= 384;
  { // WOUTP (200 blocks)
    unsigned u = blk*256u + tid; int k2 = u/400, c = u%400;
    ws[OFF_WOUTP/4 + u] = pk2(Woutm[2*k2*400+c], Woutm[(2*k2+1)*400+c]);
  }
}

// ---------- keys kernel: keysH[b][e][a] = (mem[b]@Wm)[e][a]*2log2e ----------
__global__ __launch_bounds__(256) void keys_kernel(const float* memory, const unsigned* wm4, __half* keysH)
{
  int tid = threadIdx.x;
  int b = blockIdx.x >> 3, et = blockIdx.x & 7, e0 = et*32, a = tid;
  __shared__ __align__(16) unsigned a2[32][4];
  float acc[32];
  #pragma unroll
  for (int e=0;e<32;e++) acc[e]=0.f;
  for (int kc=0;kc<32;kc++){
    if (tid < 128){
      int e = tid>>2, i = tid&3;
      const float* mr = memory + (size_t)(b*256 + e0+e)*256 + 8*kc + 2*i;
      a2[e][i] = pk2(mr[0], mr[1]);
    }
    __syncthreads();
    uint4 wv = ((const uint4*)wm4)[kc*256 + a];
    #pragma unroll
    for (int e=0;e<32;e++){ uint4 uv = *((const uint4*)a2[e]); DOT4(acc[e], uv, wv); }
    __syncthreads();
  }
  __half* base = keysH + (size_t)(b*256 + e0)*256;
  #pragma unroll
  for (int e=0;e<32;e++) base[(size_t)e*256 + a] = __float2half(acc[e]*2.88539008f);
}

// ---------- xg kernel ----------
__global__ __launch_bounds__(768) void xg_kernel(const float* inputs, const float* bdec,
                                                 const unsigned* wxx4, __half* xg)
{
  int tid = threadIdx.x;
  int b = blockIdx.x >> 3, t0 = (blockIdx.x & 7)*25;
  __shared__ __align__(16) unsigned xp[25][200];
  for (int idx = tid; idx < 5000; idx += 768){
    int tt = idx/200, kk = idx%200;
    float2 v = ((const float2*)(inputs + (size_t)(b*200 + t0+tt)*400))[kk];
    xp[tt][kk] = pk2(v.x, v.y);
  }
  __syncthreads();
  int c = tid;
  float bd = bdec[c];
  float acc[25];
  #pragma unroll
  for (int tt=0;tt<25;tt++) acc[tt]=bd;
  for (int kc=0;kc<50;kc++){
    uint4 wv = ((const uint4*)wxx4)[kc*768 + c];
    #pragma unroll
    for (int tt=0;tt<25;tt++){ uint4 xv = ((const uint4*)xp[tt])[kc]; DOT4(acc[tt], xv, wv); }
  }
  __half* xr = xg + (size_t)b*153600;
  #pragma unroll
  for (int tt=0;tt<25;tt++) xr[(size_t)(t0+tt)*768 + c] = __float2half(acc[tt]);
}

// ---------- decoder: 256 wgs = 32 groups x 8 members, 512 thr ----------
__global__ __launch_bounds__(512, 2) void decoder_kernel(
    const float* va, const unsigned* gw4, const unsigned* qw4, const unsigned* alw4,
    const unsigned* mem4, const unsigned* keysU, const __half* xgAll,
    unsigned* attn2, float* out, unsigned* cnt,
    float* hbuf, float* qpart, float* scbuf, float* apart)
{
  const int tid = threadIdx.x;
  const int b = blockIdx.x & 31, m = blockIdx.x >> 5;

  // ---- resident weights ----
  unsigned wgt[64];
  { int j = tid>>4, g=(tid>>2)&3, s=tid&3;
    if (g<3){
      int base = (((m*32+j)*3+g)*4+s)*64;
      #pragma unroll
      for (int i=0;i<64;i++) wgt[i] = gw4[base+i];
    } else {
      #pragma unroll
      for (int i=0;i<64;i++) wgt[i] = 0u;
    } }
  unsigned wq[8];
  { int base = ((m*256 + (tid>>1))*2 + (tid&1))*8;
    #pragma unroll
    for (int i=0;i<8;i++) wq[i] = qw4[base+i]; }
  unsigned kk[8];
  { int base = ((b*256 + m*32 + (tid>>4))*128) + (tid&15)*8;
    #pragma unroll
    for (int i=0;i<8;i++) kk[i] = keysU[base+i]; }
  unsigned mmr[8];
  { int base = (((b*8+m)*32 + (tid>>4))*16 + (tid&15))*8;
    #pragma unroll
    for (int i=0;i<8;i++) mmr[i] = mem4[base+i]; }
  unsigned aw[16];
  { int base = ((m*256 + (tid>>1))*2 + (tid&1))*16;
    #pragma unroll
    for (int i=0;i<16;i++) aw[i] = alw4[base+i]; }

  __shared__ float vf[256], qf[256], alf[256], aff[256];
  __shared__ float gz[32], gr[32], gnx[32], gnh[32], hff[32], cfs[32], red[16];
  __shared__ __align__(16) unsigned attnp[128], h2s[128], al2[128], hop[16], ctxp[16];
  __shared__ float trp[200][33];
  __shared__ float VsumS;

  const __half* xgb = xgAll + (size_t)b*153600;
  unsigned* attn2b = attn2 + (size_t)b*25600;
  float* hbufb = hbuf + b*256;
  float* qpb = qpart + b*2048;
  float* scb = scbuf + b*256;
  float* apb = apart + b*2048;
  unsigned* cg = cnt + b*64;   // 256B-padded counter slot per group (false-sharing fix)

  if (tid<256) vf[tid]=va[tid];
  if (tid<128){ attnp[tid]=0u; h2s[tid]=0u; }
  __syncthreads();
  { float vs = (tid<256)? vf[tid] : 0.f;
    #pragma unroll
    for (int off=32; off; off>>=1) vs += __shfl_xor(vs, off);
    if ((tid&63)==0) red[tid>>6]=vs;
    __syncthreads();
    if (tid==0){ float s2=0; for (int i=0;i<8;i++) s2+=red[i]; VsumS=s2; }
    __syncthreads(); }

  float h_own = 0.f;
  unsigned tgt = 0;

  for (int t=0; t<TDEC; t++){
    // recon attn(t-1) from apart partials
    if (t>0){
      if (tid<256){
        float s2=0;
        #pragma unroll
        for (int mm2=0;mm2<8;mm2++) s2 += gloadf(apb + mm2*256 + tid);
        aff[tid]=s2;
      }
      __syncthreads();
      if (tid<128){
        unsigned u = pk2(aff[2*tid], aff[2*tid+1]);
        attnp[tid]=u;
        if (m==0) gstoreu(attn2b + (t-1)*128 + tid, u);
      }
      __syncthreads();
    }
    // P1 gates
    { int j=tid>>4, g=(tid>>2)&3, s=tid&3;
      if (g<3){
        float acc=0.f;
        const unsigned* opb = (s&2)? h2s : attnp;
        int off = (s&1)*64;
        #pragma unroll
        for (int i=0;i<64;i++) acc = fdot2u(opb[off+i], wgt[i], acc);
        float o1 = __shfl_xor(acc,1);
        acc += o1;
        if (g<2){
          acc += __shfl_xor(acc,2);
          if (s==0){
            float xgv = __half2float(xgb[(size_t)t*768 + g*256 + m*32 + j]);
            if (g==0) gz[j] = acc + xgv; else gr[j] = acc + xgv;
          }
        } else {
          if (s==0){ float xgv = __half2float(xgb[(size_t)t*768 + 512 + m*32 + j]); gnx[j] = acc + xgv; }
          if (s==2) gnh[j] = acc;
        }
      } }
    __syncthreads();
    // P2 h update
    if (tid<32){
      int j=tid;
      float z = sigf(gz[j]);
      float r = sigf(gr[j]);
      float n = tanhf_(gnx[j] + r*gnh[j]);
      float hn = z*h_own + (1.f-z)*n;
      h_own = hn;
      hff[j] = hn;
      gstoref(hbufb + m*32 + j, hn);
    }
    __syncthreads();
    if (tid<16) hop[tid] = pk2(hff[2*tid], hff[2*tid+1]);
    __syncthreads();
    // P3a q partial (Wq K-rows of own h-slice)
    { int a=tid>>1, s2=tid&1;
      float acc=0.f;
      #pragma unroll
      for (int i=0;i<8;i++) acc = fdot2u(hop[s2*8+i], wq[i], acc);
      acc += __shfl_xor(acc,1);
      if (s2==0) gstoref(qpb + m*256 + a, acc);
    }
    __syncthreads();
    // sync1
    tgt += 8;
    if (tid==0){
      __threadfence();
      __hip_atomic_fetch_add(cg, 1u, __ATOMIC_RELEASE, AG);
      while (__hip_atomic_load(cg, __ATOMIC_ACQUIRE, AG) < tgt) __builtin_amdgcn_s_sleep(1);
    }
    __syncthreads();
    // gather h (thr 0..255) and q (thr 256..511)
    if (tid<256) aff[tid] = gloadf(hbufb + tid);
    else { int a = tid-256; float s2=0;
      #pragma unroll
      for (int mm2=0;mm2<8;mm2++) s2 += gloadf(qpb + mm2*256 + a);
      qf[a] = s2*2.88539008f; }
    __syncthreads();
    if (tid<128) h2s[tid] = pk2(aff[2*tid], aff[2*tid+1]);
    __syncthreads();
    // P4 scores (keys resident)
    { int e=tid>>4, at=tid&15;
      float acc=0.f;
      #pragma unroll
      for (int i=0;i<8;i++){
        int a0 = at*16 + 2*i;
        float w0 = FEXP2(lo2(kk[i]) + qf[a0]);   acc = fmaf(vf[a0],   FRCP(1.f+w0), acc);
        float w1 = FEXP2(hi2(kk[i]) + qf[a0+1]); acc = fmaf(vf[a0+1], FRCP(1.f+w1), acc);
      }
      acc += __shfl_xor(acc,1); acc += __shfl_xor(acc,2);
      acc += __shfl_xor(acc,4); acc += __shfl_xor(acc,8);
      if (at==0) gstoref(scb + m*32 + e, VsumS - 2.f*acc);
    }
    __syncthreads();
    // sync2
    tgt += 8;
    if (tid==0){
      __threadfence();
      __hip_atomic_fetch_add(cg, 1u, __ATOMIC_RELEASE, AG);
      while (__hip_atomic_load(cg, __ATOMIC_ACQUIRE, AG) < tgt) __builtin_amdgcn_s_sleep(1);
    }
    __syncthreads();
    // replicated softmax
    { float x = (tid<256)? gloadf(scb + tid) : -3.0e38f;
      float mx = x;
      #pragma unroll
      for (int off=32; off; off>>=1) mx = fmaxf(mx, __shfl_xor(mx, off));
      if ((tid&63)==0) red[tid>>6] = mx;
      __syncthreads();
      float gm = fmaxf(fmaxf(fmaxf(red[0],red[1]),fmaxf(red[2],red[3])),
                       fmaxf(fmaxf(red[4],red[5]),fmaxf(red[6],red[7])));
      float p = (tid<256)? FEXP2((x-gm)*1.44269504f) : 0.f;
      float ss = p;
      #pragma unroll
      for (int off=32; off; off>>=1) ss += __shfl_xor(ss, off);
      if ((tid&63)==0) red[8+(tid>>6)] = ss;
      __syncthreads();
      float S = (red[8]+red[9])+(red[10]+red[11])+(red[12]+red[13])+(red[14]+red[15]);
      if (tid<256) alf[tid] = p * FRCP(S);
    }
    __syncthreads();
    if (tid<128) al2[tid] = pk2(alf[2*tid], alf[2*tid+1]);
    if (tid<32) trp[t][tid] = alf[m*32+tid];
    __syncthreads();
    // P6 ctx (mem resident)
    { int d=tid>>4, ec=tid&15;
      float acc=0.f;
      #pragma unroll
      for (int i=0;i<8;i++) acc = fdot2u(al2[ec*8+i], mmr[i], acc);
      acc += __shfl_xor(acc,1); acc += __shfl_xor(acc,2);
      acc += __shfl_xor(acc,4); acc += __shfl_xor(acc,8);
      if (ec==0) cfs[d]=acc;
    }
    __syncthreads();
    if (tid<16) ctxp[tid] = pk2(cfs[2*tid], cfs[2*tid+1]);
    __syncthreads();
    // P7 attn K-partials
    { int s3=tid&1;
      const unsigned* ob = s3? ctxp : hop;
      float acc=0.f;
      #pragma unroll
      for (int i=0;i<16;i++) acc = fdot2u(ob[i], aw[i], acc);
      acc += __shfl_xor(acc,1);
      if (s3==0) gstoref(apb + m*256 + (tid>>1), acc);
    }
    __syncthreads();
    // sync3
    tgt += 8;
    if (tid==0){
      __threadfence();
      __hip_atomic_fetch_add(cg, 1u, __ATOMIC_RELEASE, AG);
      while (__hip_atomic_load(cg, __ATOMIC_ACQUIRE, AG) < tgt) __builtin_amdgcn_s_sleep(1);
    }
    __syncthreads();
  }

  // epilogue: final attn(199)
  if (tid<256){
    float s2=0;
    #pragma unroll
    for (int mm2=0;mm2<8;mm2++) s2 += gloadf(apb + mm2*256 + tid);
    aff[tid]=s2;
  }
  __syncthreads();
  if (tid<128 && m==0) gstoreu(attn2b + 199*128 + tid, pk2(aff[2*tid], aff[2*tid+1]));
  // alignments transpose: member m writes its e-slice coalesced along t
  for (int e=0;e<32;e++){
    for (int tt=tid; tt<200; tt+=512)
      out[AOFF + (size_t)b*51200 + (size_t)(m*32+e)*200 + tt] = trp[tt][e];
  }
}

// ---------- GRU kernel (f16 I/O): 32 groups x 8 members ----------
__global__ __launch_bounds__(256) void gru_kernel(
    const unsigned* xa2, const unsigned* xb2,
    const unsigned* Wxp, const unsigned* Whp, const float* bias,
    unsigned* ye2, unsigned* cnt,
    const unsigned* Woutp, const float* bout, float* melout)
{
  const int tid = threadIdx.x;
  const int b = blockIdx.x & 31, m = blockIdx.x >> 5;
  const int c = (tid<192)? tid%96 : 0, s = (tid<192)? tid/96 : 0;
  const int col = (c>>5)*256 + m*32 + (c&31);

  unsigned wx[64], wh[64];
  if (tid<192){
    #pragma unroll
    for (int i=0;i<64;i++){ wx[i] = Wxp[(size_t)(s*64+i)*768 + col]; wh[i] = Whp[(size_t)(s*64+i)*768 + col]; }
  }
  unsigned wo[32];
  if (Woutp && tid<200){
    int mc = m*50 + tid%50, so = tid/50;
    #pragma unroll
    for (int i=0;i<32;i++) wo[i] = Woutp[(size_t)(so*32+i)*400 + mc];
  }
  __shared__ float bsl[96], bml[50];
  __shared__ __align__(16) float o1f[256];
  __shared__ __align__(16) unsigned h2[128], in2[128];
  __shared__ float pax[192], pah[192], pm[200];
  if (tid<96) bsl[tid] = bias[(tid>>5)*256 + m*32 + (tid&31)];
  if (Woutp && tid<50) bml[tid] = bout[m*50+tid];
  if (tid<128) h2[tid]=0u;
  __syncthreads();

  const unsigned* xa = xa2 + (size_t)b*25600;
  const unsigned* xb = xb2 ? xb2 + (size_t)b*25600 : nullptr;
  unsigned* ye = ye2 + (size_t)b*25600;
  unsigned* cg = cnt + b*64;   // 256B-padded counter slot per group
  float h_own = 0.f;

  for (int t=0;t<TDEC;t++){
    if (tid<128){
      unsigned ua = xa[t*128+tid];
      if (xb){
        unsigned ub = xb[t*128+tid];
        float x0 = lo2(ua)+lo2(ub), x1 = hi2(ua)+hi2(ub);
        o1f[2*tid]=x0; o1f[2*tid+1]=x1;
        in2[tid]=pk2(x0,x1);
      } else in2[tid]=ua;
    }
    __syncthreads();
    if (tid<192){
      float ax=0.f, ah=0.f;
      #pragma unroll
      for (int i4=0;i4<16;i4++){
        uint4 uv = ((const uint4*)in2)[s*16+i4];
        ax = fdot2u(uv.x, wx[i4*4+0], ax); ax = fdot2u(uv.y, wx[i4*4+1], ax);
        ax = fdot2u(uv.z, wx[i4*4+2], ax); ax = fdot2u(uv.w, wx[i4*4+3], ax);
        uint4 vv = ((const uint4*)h2)[s*16+i4];
        ah = fdot2u(vv.x, wh[i4*4+0], ah); ah = fdot2u(vv.y, wh[i4*4+1], ah);
        ah = fdot2u(vv.z, wh[i4*4+2], ah); ah = fdot2u(vv.w, wh[i4*4+3], ah);
      }
      pax[tid]=ax; pah[tid]=ah;
    }
    __syncthreads();
    if (tid<32){
      int j=tid;
      float z = sigf(pax[j]    + pax[96+j]  + bsl[j]    + pah[j]    + pah[96+j]);
      float r = sigf(pax[32+j] + pax[128+j] + bsl[32+j] + pah[32+j] + pah[128+j]);
      float n = tanhf_(pax[64+j] + pax[160+j] + bsl[64+j] + r*(pah[64+j] + pah[160+j]));
      float hn = z*h_own + (1.f-z)*n;
      h_own = hn;
      float hp = __shfl_xor(hn, 1);
      if ((tid&1)==0) gstoreu(ye + t*128 + m*16 + (tid>>1), pk2(hn, hp));
    }
    __syncthreads();
    if (tid==0){
      __threadfence();
      __hip_atomic_fetch_add(cg, 1u, __ATOMIC_RELEASE, AG);
      unsigned tgt2 = 8u*(t+1);
      while (__hip_atomic_load(cg, __ATOMIC_ACQUIRE, AG) < tgt2) __builtin_amdgcn_s_sleep(1);
    }
    __syncthreads();
    if (tid<128) h2[tid] = gloadu(ye + t*128 + tid);
    __syncthreads();
    if (Woutp){
      if (tid<128) in2[tid] = pk2(o1f[2*tid]+lo2(h2[tid]), o1f[2*tid+1]+hi2(h2[tid]));
      __syncthreads();
      if (tid<200){
        int so = tid/50;
        float acc=0.f;
        #pragma unroll
        for (int i4=0;i4<8;i4++){
          uint4 uv = ((const uint4*)in2)[so*8+i4];
          acc = fdot2u(uv.x, wo[i4*4+0], acc); acc = fdot2u(uv.y, wo[i4*4+1], acc);
          acc = fdot2u(uv.z, wo[i4*4+2], acc); acc = fdot2u(uv.w, wo[i4*4+3], acc);
        }
        pm[tid]=acc;
      }
      __syncthreads();
      if (tid<50){
        float mel = pm[tid]+pm[50+tid]+pm[100+tid]+pm[150+tid]+bml[tid];
        melout[(size_t)b*80000 + (size_t)t*400 + m*50 + tid] = mel;
      }
      __syncthreads();
    }
  }
}

// ---------- launch ----------
extern "C" void kernel_launch(void* const* d_in, const int* in_sizes, int n_in,
                              void* d_out, int out_size, void* d_ws, size_t ws_size,
                              hipStream_t stream) {
  if (ws_size < WS_NEED) return;
  const float* inputs = (const float*)d_in[0];
  const float* memory = (const float*)d_in[1];
  const float* Wq  = (const float*)d_in[2];
  const float* Wm  = (const float*)d_in[3];
  const float* va  = (const float*)d_in[4];
  const float* Wal = (const float*)d_in[5];
  const float* Wxd = (const float*)d_in[6];
  const float* Whd = (const float*)d_in[7];
  const float* bdec= (const float*)d_in[8];
  const float* Wx1 = (const float*)d_in[9];
  const float* Wh1 = (const float*)d_in[10];
  const float* b1  = (const float*)d_in[11];
  const float* Wx2 = (const float*)d_in[12];
  const float* Wh2 = (const float*)d_in[13];
  const float* b2  = (const float*)d_in[14];
  const float* Wout= (const float*)d_in[15];
  const float* bout= (const float*)d_in[16];
  float* out = (float*)d_out;

  char* wsb = (char*)d_ws;
  unsigned* wsu = (unsigned*)d_ws;
  const unsigned* WXX4 = (const unsigned*)(wsb + OFF_WXX4);
  const unsigned* GW4  = (const unsigned*)(wsb + OFF_GW4);
  const unsigned* QW4  = (const unsigned*)(wsb + OFF_QW4);
  const unsigned* ALW4 = (const unsigned*)(wsb + OFF_ALW4);
  const unsigned* MEM4 = (const unsigned*)(wsb + OFF_MEM4);
  const unsigned* WM4  = (const unsigned*)(wsb + OFF_WM4);
  const unsigned* WX1P = (const unsigned*)(wsb + OFF_WX1P);
  const unsigned* WH1P = (const unsigned*)(wsb + OFF_WH1P);
  const unsigned* WX2P = (const unsigned*)(wsb + OFF_WX2P);
  const unsigned* WH2P = (const unsigned*)(wsb + OFF_WH2P);
  const unsigned* WOUTP= (const unsigned*)(wsb + OFF_WOUTP);
  __half* KEYS = (__half*)(wsb + OFF_KEYS);
  __half* XG   = (__half*)(wsb + OFF_XG);
  unsigned* ATTN2 = (unsigned*)(wsb + OFF_ATTN);
  float* HBUF = (float*)(wsb + OFF_HBUF);
  float* QPART= (float*)(wsb + OFF_QPART);
  float* SCB  = (float*)(wsb + OFF_SCB);
  float* APART= (float*)(wsb + OFF_APART);
  unsigned* Y1u = (unsigned*)(wsb + OFF_Y1);
  unsigned* Y2u = (unsigned*)(wsb + OFF_Y2);
  unsigned* CNT = (unsigned*)wsb;          // 3 x 32 x 64 uints (256B-padded)

  (void)hipMemsetAsync(d_ws, 0, 24576, stream);
  pack_kernel<<<7712, 256, 0, stream>>>(Wxd, Whd, Wq, Wal, Wm, Wx1, Wh1, Wx2, Wh2, Wout, memory, wsu);
  keys_kernel<<<256, 256, 0, stream>>>(memory, WM4, KEYS);
  xg_kernel<<<256, 768, 0, stream>>>(inputs, bdec, WXX4, XG);
  decoder_kernel<<<256, 512, 0, stream>>>(va, GW4, QW4, ALW4, MEM4, (const unsigned*)KEYS, XG,
                                          ATTN2, out, CNT, HBUF, QPART, SCB, APART);
  gru_kernel<<<256, 256, 0, stream>>>(ATTN2, nullptr, WX1P, WH1P, b1, Y1u, CNT + 32*64, nullptr, nullptr, nullptr);
  gru_kernel<<<256, 256, 0, stream>>>(ATTN2, Y1u,     WX2P, WH2P, b2, Y2u, CNT + 64*64, WOUTP, bout, out);
}

// Round 12
// 6307.332 us; speedup vs baseline: 2.5056x; 1.4193x over previous
//
// AttentionDecoder on MI355X — round 12: identical to round 9/10/11 (acquire timeouts; never ran)
// Flag-based group sync (no RMW, no threadfence): per-member release-store flags (128B apart),
// 8 threads poll in parallel with acquire loads. Decoder 3 syncs/step; GRUs 1 sync/step.

#include <hip/hip_runtime.h>
#include <hip/hip_fp16.h>
#include <stdint.h>

#define TDEC 200
#define FSTRIDE 32   // uints between member flags (128B)

// ---------- ws layout (bytes) ----------
static constexpr size_t OFF_CNT  = 0;                        // 3 kernels x 32 groups x 8 flags x 128B = 98304
static constexpr size_t OFF_WXX4 = 98304;                    // [50][768][4] uint (xg staging weights)
static constexpr size_t OFF_GW4  = OFF_WXX4 + 614400;        // gates resident: 196608 uint
static constexpr size_t OFF_QW4  = OFF_GW4  + 786432;        // 32768 uint
static constexpr size_t OFF_ALW4 = OFF_QW4  + 131072;        // 65536 uint
static constexpr size_t OFF_MEM4 = OFF_ALW4 + 262144;        // 1048576 uint
static constexpr size_t OFF_WM4  = OFF_MEM4 + 4194304;       // [32][256][4] uint (keys_kernel)
static constexpr size_t OFF_WX1P = OFF_WM4  + 131072;        // [128][768] uint
static constexpr size_t OFF_WH1P = OFF_WX1P + 393216;
static constexpr size_t OFF_WX2P = OFF_WH1P + 393216;
static constexpr size_t OFF_WH2P = OFF_WX2P + 393216;
static constexpr size_t OFF_WOUTP= OFF_WH2P + 393216;        // [128][400] uint
static constexpr size_t OFF_KEYS = OFF_WOUTP + 204800;       // __half [32][256][256] plain, *2log2e
static constexpr size_t OFF_XG   = OFF_KEYS + 4194304;       // __half [32][200][768]
static constexpr size_t OFF_ATTN = OFF_XG + 9830400;         // uint(half2) [32][200][128]
static constexpr size_t OFF_HBUF = OFF_ATTN + 3276800;       // float [32][256]
static constexpr size_t OFF_QPART= OFF_HBUF + 32768;         // float [32][8][256]
static constexpr size_t OFF_SCB  = OFF_QPART + 262144;       // float [32][256]
static constexpr size_t OFF_APART= OFF_SCB + 32768;          // float [32][8][256]
static constexpr size_t WS_NEED  = OFF_APART + 262144;       // ~24.7 MiB
// aliases (dead regions by GRU time): Y1 in KEYS, Y2 in XG — each uint[32][200][128]
static constexpr size_t OFF_Y1   = OFF_KEYS;
static constexpr size_t OFF_Y2   = OFF_XG;

#define AOFF 2560000   // alignments offset in d_out (floats)

// ---------- helpers ----------
#if __has_builtin(__builtin_amdgcn_exp2f)
#define FEXP2(x) __builtin_amdgcn_exp2f(x)
#else
#define FEXP2(x) exp2f(x)
#endif
#if __has_builtin(__builtin_amdgcn_rcpf)
#define FRCP(x) __builtin_amdgcn_rcpf(x)
#else
#define FRCP(x) (1.0f/(x))
#endif

typedef _Float16 h2t __attribute__((ext_vector_type(2)));

static __device__ __forceinline__ float fdot2u(unsigned a, unsigned b, float c){
  return __builtin_amdgcn_fdot2(__builtin_bit_cast(h2t, a), __builtin_bit_cast(h2t, b), c, false);
}
static __device__ __forceinline__ unsigned pk2(float a, float b){
  auto r = __builtin_amdgcn_cvt_pkrtz(a, b);
  return __builtin_bit_cast(unsigned, r);
}
static __device__ __forceinline__ float lo2(unsigned u){ h2t h = __builtin_bit_cast(h2t,u); return (float)h[0]; }
static __device__ __forceinline__ float hi2(unsigned u){ h2t h = __builtin_bit_cast(h2t,u); return (float)h[1]; }
static __device__ __forceinline__ float sigf(float x){ return FRCP(1.f + FEXP2(x * -1.44269504f)); }
static __device__ __forceinline__ float tanhf_(float x){ return 1.f - 2.f * FRCP(1.f + FEXP2(x * 2.88539008f)); }
#define DOT4(acc, U_, W_) do{ acc = fdot2u((U_).x,(W_).x,acc); acc = fdot2u((U_).y,(W_).y,acc); \
                              acc = fdot2u((U_).z,(W_).z,acc); acc = fdot2u((U_).w,(W_).w,acc);}while(0)
#define AG __HIP_MEMORY_SCOPE_AGENT
static __device__ __forceinline__ void gstoref(float* p, float v){ __hip_atomic_store(p, v, __ATOMIC_RELAXED, AG); }
static __device__ __forceinline__ float gloadf(const float* p){ return __hip_atomic_load(p, __ATOMIC_RELAXED, AG); }
static __device__ __forceinline__ void gstoreu(unsigned* p, unsigned v){ __hip_atomic_store(p, v, __ATOMIC_RELAXED, AG); }
static __device__ __forceinline__ unsigned gloadu(const unsigned* p){ return __hip_atomic_load(p, __ATOMIC_RELAXED, AG); }

// flag-based group sync: prior __syncthreads has drained all agent-coherent data
// stores; member m release-stores its flag=v; threads 0..7 acquire-poll all 8 flags.
static __device__ __forceinline__ void group_sync(unsigned* gflags, int m, unsigned v, int tid){
  if (tid==0) __hip_atomic_store(gflags + m*FSTRIDE, v, __ATOMIC_RELEASE, AG);
  if (tid<8){
    while (__hip_atomic_load(gflags + tid*FSTRIDE, __ATOMIC_ACQUIRE, AG) < v)
      __builtin_amdgcn_s_sleep(1);
  }
  __syncthreads();
}

// ---------- pack kernel ----------
__global__ __launch_bounds__(256) void pack_kernel(
    const float* Wxd, const float* Whd, const float* Wqm, const float* Walm, const float* Wmm,
    const float* Wx1, const float* Wh1, const float* Wx2, const float* Wh2, const float* Woutm,
    const float* memory, unsigned* ws)
{
  int blk = blockIdx.x, tid = threadIdx.x;
  if (blk < 600){ // WXX4: rows 0..399 of Wx_dec, [kc][768][4]
    unsigned u = blk*256u + tid; int kc = u/3072, r = u%3072, c = r>>2, i = r&3, row = 8*kc+2*i;
    ws[OFF_WXX4/4 + u] = pk2(Wxd[row*768+c], Wxd[(row+1)*768+c]); return; } blk -= 600;
  if (blk < 768){ // GW4: member-resident gate weights (WxA rows 400.. for kp<128, Wh for kp>=128)
    unsigned u = blk*256u + tid;
    int m = u/24576, r = u%24576, j = r/768, r2 = r%768, g = r2>>8, r3 = r2&255, s = r3>>6, i = r3&63;
    int kp = s*64 + i, col = g*256 + m*32 + j;
    float v0, v1;
    if (kp < 128){ int row = 400 + 2*kp; v0 = Wxd[row*768+col]; v1 = Wxd[(row+1)*768+col]; }
    else         { int row = 2*(kp-128); v0 = Whd[row*768+col]; v1 = Whd[(row+1)*768+col]; }
    ws[OFF_GW4/4 + u] = pk2(v0, v1); return; } blk -= 768;
  if (blk < 128){ // QW4: Wq K-rows per member, j-pairs
    unsigned u = blk*256u + tid;
    int m = u>>12, a = (u>>4)&255, s2 = (u>>3)&1, i = u&7;
    int j0 = m*32 + (s2*8+i)*2;
    ws[OFF_QW4/4 + u] = pk2(Wqm[j0*256+a], Wqm[(j0+1)*256+a]); return; } blk -= 128;
  if (blk < 256){ // ALW4: Wal K-rows (h-slice s3=0, ctx-slice s3=1)
    unsigned u = blk*256u + tid;
    int m = u>>13, c = (u>>5)&255, s3 = (u>>4)&1, i = u&15;
    int row0 = (s3 ? 256 + m*32 : m*32) + 2*i;
    ws[OFF_ALW4/4 + u] = pk2(Walm[row0*256+c], Walm[(row0+1)*256+c]); return; } blk -= 256;
  if (blk < 4096){ // MEM4: memory e-pairs x member d-slice
    unsigned u = blk*256u + tid;
    int b = u>>15, m = (u>>12)&7, d = (u>>7)&31, ec = (u>>3)&15, i = u&7;
    int e0 = (ec*8+i)*2, col = m*32 + d;
    ws[OFF_MEM4/4 + u] = pk2(memory[((size_t)(b*256+e0))*256+col],
                             memory[((size_t)(b*256+e0+1))*256+col]); return; } blk -= 4096;
  if (blk < 128){ // WM4 (keys_kernel)
    unsigned u = blk*256u + tid; int kc = u>>10, c = (u>>2)&255, i = u&3, row = 8*kc+2*i;
    ws[OFF_WM4/4 + u] = pk2(Wmm[row*256+c], Wmm[(row+1)*256+c]); return; } blk -= 128;
  if (blk < 384){ unsigned u = blk*256u + tid; int k2 = u/768, c = u%768;
    ws[OFF_WX1P/4 + u] = pk2(Wx1[2*k2*768+c], Wx1[(2*k2+1)*768+c]); return; } blk -= 384;
  if (blk < 384){ unsigned u = blk*256u + tid; int k2 = u/768, c = u%768;
    ws[OFF_WH1P/4 + u] = pk2(Wh1[2*k2*768+c], Wh1[(2*k2+1)*768+c]); return; } blk -= 384;
  if (blk < 384){ unsigned u = blk*256u + tid; int k2 = u/768, c = u%768;
    ws[OFF_WX2P/4 + u] = pk2(Wx2[2*k2*768+c], Wx2[(2*k2+1)*768+c]); return; } blk -= 384;
  if (blk < 384){ unsigned u = blk*256u + tid; int k2 = u/768, c = u%768;
    ws[OFF_WH2P/4 + u] = pk2(Wh2[2*k2*768+c], Wh2[(2*k2+1)*768+c]); return; } blk -= 384;
  { // WOUTP (200 blocks)
    unsigned u = blk*256u + tid; int k2 = u/400, c = u%400;
    ws[OFF_WOUTP/4 + u] = pk2(Woutm[2*k2*400+c], Woutm[(2*k2+1)*400+c]);
  }
}

// ---------- keys kernel: keysH[b][e][a] = (mem[b]@Wm)[e][a]*2log2e ----------
__global__ __launch_bounds__(256) void keys_kernel(const float* memory, const unsigned* wm4, __half* keysH)
{
  int tid = threadIdx.x;
  int b = blockIdx.x >> 3, et = blockIdx.x & 7, e0 = et*32, a = tid;
  __shared__ __align__(16) unsigned a2[32][4];
  float acc[32];
  #pragma unroll
  for (int e=0;e<32;e++) acc[e]=0.f;
  for (int kc=0;kc<32;kc++){
    if (tid < 128){
      int e = tid>>2, i = tid&3;
      const float* mr = memory + (size_t)(b*256 + e0+e)*256 + 8*kc + 2*i;
      a2[e][i] = pk2(mr[0], mr[1]);
    }
    __syncthreads();
    uint4 wv = ((const uint4*)wm4)[kc*256 + a];
    #pragma unroll
    for (int e=0;e<32;e++){ uint4 uv = *((const uint4*)a2[e]); DOT4(acc[e], uv, wv); }
    __syncthreads();
  }
  __half* base = keysH + (size_t)(b*256 + e0)*256;
  #pragma unroll
  for (int e=0;e<32;e++) base[(size_t)e*256 + a] = __float2half(acc[e]*2.88539008f);
}

// ---------- xg kernel ----------
__global__ __launch_bounds__(768) void xg_kernel(const float* inputs, const float* bdec,
                                                 const unsigned* wxx4, __half* xg)
{
  int tid = threadIdx.x;
  int b = blockIdx.x >> 3, t0 = (blockIdx.x & 7)*25;
  __shared__ __align__(16) unsigned xp[25][200];
  for (int idx = tid; idx < 5000; idx += 768){
    int tt = idx/200, kk = idx%200;
    float2 v = ((const float2*)(inputs + (size_t)(b*200 + t0+tt)*400))[kk];
    xp[tt][kk] = pk2(v.x, v.y);
  }
  __syncthreads();
  int c = tid;
  float bd = bdec[c];
  float acc[25];
  #pragma unroll
  for (int tt=0;tt<25;tt++) acc[tt]=bd;
  for (int kc=0;kc<50;kc++){
    uint4 wv = ((const uint4*)wxx4)[kc*768 + c];
    #pragma unroll
    for (int tt=0;tt<25;tt++){ uint4 xv = ((const uint4*)xp[tt])[kc]; DOT4(acc[tt], xv, wv); }
  }
  __half* xr = xg + (size_t)b*153600;
  #pragma unroll
  for (int tt=0;tt<25;tt++) xr[(size_t)(t0+tt)*768 + c] = __float2half(acc[tt]);
}

// ---------- decoder: 256 wgs = 32 groups x 8 members, 512 thr ----------
__global__ __launch_bounds__(512, 2) void decoder_kernel(
    const float* va, const unsigned* gw4, const unsigned* qw4, const unsigned* alw4,
    const unsigned* mem4, const unsigned* keysU, const __half* xgAll,
    unsigned* attn2, float* out, unsigned* cnt,
    float* hbuf, float* qpart, float* scbuf, float* apart)
{
  const int tid = threadIdx.x;
  const int b = blockIdx.x & 31, m = blockIdx.x >> 5;

  // ---- resident weights ----
  unsigned wgt[64];
  { int j = tid>>4, g=(tid>>2)&3, s=tid&3;
    if (g<3){
      int base = (((m*32+j)*3+g)*4+s)*64;
      #pragma unroll
      for (int i=0;i<64;i++) wgt[i] = gw4[base+i];
    } else {
      #pragma unroll
      for (int i=0;i<64;i++) wgt[i] = 0u;
    } }
  unsigned wq[8];
  { int base = ((m*256 + (tid>>1))*2 + (tid&1))*8;
    #pragma unroll
    for (int i=0;i<8;i++) wq[i] = qw4[base+i]; }
  unsigned kk[8];
  { int base = ((b*256 + m*32 + (tid>>4))*128) + (tid&15)*8;
    #pragma unroll
    for (int i=0;i<8;i++) kk[i] = keysU[base+i]; }
  unsigned mmr[8];
  { int base = (((b*8+m)*32 + (tid>>4))*16 + (tid&15))*8;
    #pragma unroll
    for (int i=0;i<8;i++) mmr[i] = mem4[base+i]; }
  unsigned aw[16];
  { int base = ((m*256 + (tid>>1))*2 + (tid&1))*16;
    #pragma unroll
    for (int i=0;i<16;i++) aw[i] = alw4[base+i]; }

  __shared__ float vf[256], qf[256], alf[256], aff[256];
  __shared__ float gz[32], gr[32], gnx[32], gnh[32], hff[32], cfs[32], red[16];
  __shared__ __align__(16) unsigned attnp[128], h2s[128], al2[128], hop[16], ctxp[16];
  __shared__ float trp[200][33];
  __shared__ float VsumS;

  const __half* xgb = xgAll + (size_t)b*153600;
  unsigned* attn2b = attn2 + (size_t)b*25600;
  float* hbufb = hbuf + b*256;
  float* qpb = qpart + b*2048;
  float* scb = scbuf + b*256;
  float* apb = apart + b*2048;
  unsigned* gflags = cnt + b*8*FSTRIDE;   // 8 member flags, 128B apart

  if (tid<256) vf[tid]=va[tid];
  if (tid<128){ attnp[tid]=0u; h2s[tid]=0u; }
  __syncthreads();
  { float vs = (tid<256)? vf[tid] : 0.f;
    #pragma unroll
    for (int off=32; off; off>>=1) vs += __shfl_xor(vs, off);
    if ((tid&63)==0) red[tid>>6]=vs;
    __syncthreads();
    if (tid==0){ float s2=0; for (int i=0;i<8;i++) s2+=red[i]; VsumS=s2; }
    __syncthreads(); }

  float h_own = 0.f;

  for (int t=0; t<TDEC; t++){
    // recon attn(t-1) from apart partials
    if (t>0){
      if (tid<256){
        float s2=0;
        #pragma unroll
        for (int mm2=0;mm2<8;mm2++) s2 += gloadf(apb + mm2*256 + tid);
        aff[tid]=s2;
      }
      __syncthreads();
      if (tid<128){
        unsigned u = pk2(aff[2*tid], aff[2*tid+1]);
        attnp[tid]=u;
        if (m==0) gstoreu(attn2b + (t-1)*128 + tid, u);
      }
      __syncthreads();
    }
    // P1 gates
    { int j=tid>>4, g=(tid>>2)&3, s=tid&3;
      if (g<3){
        float acc=0.f;
        const unsigned* opb = (s&2)? h2s : attnp;
        int off = (s&1)*64;
        #pragma unroll
        for (int i=0;i<64;i++) acc = fdot2u(opb[off+i], wgt[i], acc);
        float o1 = __shfl_xor(acc,1);
        acc += o1;
        if (g<2){
          acc += __shfl_xor(acc,2);
          if (s==0){
            float xgv = __half2float(xgb[(size_t)t*768 + g*256 + m*32 + j]);
            if (g==0) gz[j] = acc + xgv; else gr[j] = acc + xgv;
          }
        } else {
          if (s==0){ float xgv = __half2float(xgb[(size_t)t*768 + 512 + m*32 + j]); gnx[j] = acc + xgv; }
          if (s==2) gnh[j] = acc;
        }
      } }
    __syncthreads();
    // P2 h update
    if (tid<32){
      int j=tid;
      float z = sigf(gz[j]);
      float r = sigf(gr[j]);
      float n = tanhf_(gnx[j] + r*gnh[j]);
      float hn = z*h_own + (1.f-z)*n;
      h_own = hn;
      hff[j] = hn;
      gstoref(hbufb + m*32 + j, hn);
    }
    __syncthreads();
    if (tid<16) hop[tid] = pk2(hff[2*tid], hff[2*tid+1]);
    __syncthreads();
    // P3a q partial (Wq K-rows of own h-slice)
    { int a=tid>>1, s2=tid&1;
      float acc=0.f;
      #pragma unroll
      for (int i=0;i<8;i++) acc = fdot2u(hop[s2*8+i], wq[i], acc);
      acc += __shfl_xor(acc,1);
      if (s2==0) gstoref(qpb + m*256 + a, acc);
    }
    __syncthreads();
    group_sync(gflags, m, 3u*t+1u, tid);   // sync1
    // gather h (thr 0..255) and q (thr 256..511)
    if (tid<256) aff[tid] = gloadf(hbufb + tid);
    else { int a = tid-256; float s2=0;
      #pragma unroll
      for (int mm2=0;mm2<8;mm2++) s2 += gloadf(qpb + mm2*256 + a);
      qf[a] = s2*2.88539008f; }
    __syncthreads();
    if (tid<128) h2s[tid] = pk2(aff[2*tid], aff[2*tid+1]);
    __syncthreads();
    // P4 scores (keys resident)
    { int e=tid>>4, at=tid&15;
      float acc=0.f;
      #pragma unroll
      for (int i=0;i<8;i++){
        int a0 = at*16 + 2*i;
        float w0 = FEXP2(lo2(kk[i]) + qf[a0]);   acc = fmaf(vf[a0],   FRCP(1.f+w0), acc);
        float w1 = FEXP2(hi2(kk[i]) + qf[a0+1]); acc = fmaf(vf[a0+1], FRCP(1.f+w1), acc);
      }
      acc += __shfl_xor(acc,1); acc += __shfl_xor(acc,2);
      acc += __shfl_xor(acc,4); acc += __shfl_xor(acc,8);
      if (at==0) gstoref(scb + m*32 + e, VsumS - 2.f*acc);
    }
    __syncthreads();
    group_sync(gflags, m, 3u*t+2u, tid);   // sync2
    // replicated softmax
    { float x = (tid<256)? gloadf(scb + tid) : -3.0e38f;
      float mx = x;
      #pragma unroll
      for (int off=32; off; off>>=1) mx = fmaxf(mx, __shfl_xor(mx, off));
      if ((tid&63)==0) red[tid>>6] = mx;
      __syncthreads();
      float gm = fmaxf(fmaxf(fmaxf(red[0],red[1]),fmaxf(red[2],red[3])),
                       fmaxf(fmaxf(red[4],red[5]),fmaxf(red[6],red[7])));
      float p = (tid<256)? FEXP2((x-gm)*1.44269504f) : 0.f;
      float ss = p;
      #pragma unroll
      for (int off=32; off; off>>=1) ss += __shfl_xor(ss, off);
      if ((tid&63)==0) red[8+(tid>>6)] = ss;
      __syncthreads();
      float S = (red[8]+red[9])+(red[10]+red[11])+(red[12]+red[13])+(red[14]+red[15]);
      if (tid<256) alf[tid] = p * FRCP(S);
    }
    __syncthreads();
    if (tid<128) al2[tid] = pk2(alf[2*tid], alf[2*tid+1]);
    if (tid<32) trp[t][tid] = alf[m*32+tid];
    __syncthreads();
    // P6 ctx (mem resident)
    { int d=tid>>4, ec=tid&15;
      float acc=0.f;
      #pragma unroll
      for (int i=0;i<8;i++) acc = fdot2u(al2[ec*8+i], mmr[i], acc);
      acc += __shfl_xor(acc,1); acc += __shfl_xor(acc,2);
      acc += __shfl_xor(acc,4); acc += __shfl_xor(acc,8);
      if (ec==0) cfs[d]=acc;
    }
    __syncthreads();
    if (tid<16) ctxp[tid] = pk2(cfs[2*tid], cfs[2*tid+1]);
    __syncthreads();
    // P7 attn K-partials
    { int s3=tid&1;
      const unsigned* ob = s3? ctxp : hop;
      float acc=0.f;
      #pragma unroll
      for (int i=0;i<16;i++) acc = fdot2u(ob[i], aw[i], acc);
      acc += __shfl_xor(acc,1);
      if (s3==0) gstoref(apb + m*256 + (tid>>1), acc);
    }
    __syncthreads();
    group_sync(gflags, m, 3u*t+3u, tid);   // sync3
  }

  // epilogue: final attn(199)
  if (tid<256){
    float s2=0;
    #pragma unroll
    for (int mm2=0;mm2<8;mm2++) s2 += gloadf(apb + mm2*256 + tid);
    aff[tid]=s2;
  }
  __syncthreads();
  if (tid<128 && m==0) gstoreu(attn2b + 199*128 + tid, pk2(aff[2*tid], aff[2*tid+1]));
  // alignments transpose: member m writes its e-slice coalesced along t
  for (int e=0;e<32;e++){
    for (int tt=tid; tt<200; tt+=512)
      out[AOFF + (size_t)b*51200 + (size_t)(m*32+e)*200 + tt] = trp[tt][e];
  }
}

// ---------- GRU kernel (f16 I/O): 32 groups x 8 members ----------
__global__ __launch_bounds__(256) void gru_kernel(
    const unsigned* xa2, const unsigned* xb2,
    const unsigned* Wxp, const unsigned* Whp, const float* bias,
    unsigned* ye2, unsigned* cnt,
    const unsigned* Woutp, const float* bout, float* melout)
{
  const int tid = threadIdx.x;
  const int b = blockIdx.x & 31, m = blockIdx.x >> 5;
  const int c = (tid<192)? tid%96 : 0, s = (tid<192)? tid/96 : 0;
  const int col = (c>>5)*256 + m*32 + (c&31);

  unsigned wx[64], wh[64];
  if (tid<192){
    #pragma unroll
    for (int i=0;i<64;i++){ wx[i] = Wxp[(size_t)(s*64+i)*768 + col]; wh[i] = Whp[(size_t)(s*64+i)*768 + col]; }
  }
  unsigned wo[32];
  if (Woutp && tid<200){
    int mc = m*50 + tid%50, so = tid/50;
    #pragma unroll
    for (int i=0;i<32;i++) wo[i] = Woutp[(size_t)(so*32+i)*400 + mc];
  }
  __shared__ float bsl[96], bml[50];
  __shared__ __align__(16) float o1f[256];
  __shared__ __align__(16) unsigned h2[128], in2[128];
  __shared__ float pax[192], pah[192], pm[200];
  if (tid<96) bsl[tid] = bias[(tid>>5)*256 + m*32 + (tid&31)];
  if (Woutp && tid<50) bml[tid] = bout[m*50+tid];
  if (tid<128) h2[tid]=0u;
  __syncthreads();

  const unsigned* xa = xa2 + (size_t)b*25600;
  const unsigned* xb = xb2 ? xb2 + (size_t)b*25600 : nullptr;
  unsigned* ye = ye2 + (size_t)b*25600;
  unsigned* gflags = cnt + b*8*FSTRIDE;
  float h_own = 0.f;

  for (int t=0;t<TDEC;t++){
    if (tid<128){
      unsigned ua = xa[t*128+tid];
      if (xb){
        unsigned ub = xb[t*128+tid];
        float x0 = lo2(ua)+lo2(ub), x1 = hi2(ua)+hi2(ub);
        o1f[2*tid]=x0; o1f[2*tid+1]=x1;
        in2[tid]=pk2(x0,x1);
      } else in2[tid]=ua;
    }
    __syncthreads();
    if (tid<192){
      float ax=0.f, ah=0.f;
      #pragma unroll
      for (int i4=0;i4<16;i4++){
        uint4 uv = ((const uint4*)in2)[s*16+i4];
        ax = fdot2u(uv.x, wx[i4*4+0], ax); ax = fdot2u(uv.y, wx[i4*4+1], ax);
        ax = fdot2u(uv.z, wx[i4*4+2], ax); ax = fdot2u(uv.w, wx[i4*4+3], ax);
        uint4 vv = ((const uint4*)h2)[s*16+i4];
        ah = fdot2u(vv.x, wh[i4*4+0], ah); ah = fdot2u(vv.y, wh[i4*4+1], ah);
        ah = fdot2u(vv.z, wh[i4*4+2], ah); ah = fdot2u(vv.w, wh[i4*4+3], ah);
      }
      pax[tid]=ax; pah[tid]=ah;
    }
    __syncthreads();
    if (tid<32){
      int j=tid;
      float z = sigf(pax[j]    + pax[96+j]  + bsl[j]    + pah[j]    + pah[96+j]);
      float r = sigf(pax[32+j] + pax[128+j] + bsl[32+j] + pah[32+j] + pah[128+j]);
      float n = tanhf_(pax[64+j] + pax[160+j] + bsl[64+j] + r*(pah[64+j] + pah[160+j]));
      float hn = z*h_own + (1.f-z)*n;
      h_own = hn;
      float hp = __shfl_xor(hn, 1);
      if ((tid&1)==0) gstoreu(ye + t*128 + m*16 + (tid>>1), pk2(hn, hp));
    }
    __syncthreads();
    // flag sync (1 per step)
    if (tid==0) __hip_atomic_store(gflags + m*FSTRIDE, (unsigned)(t+1), __ATOMIC_RELEASE, AG);
    if (tid<8){
      while (__hip_atomic_load(gflags + tid*FSTRIDE, __ATOMIC_ACQUIRE, AG) < (unsigned)(t+1))
        __builtin_amdgcn_s_sleep(1);
    }
    __syncthreads();
    if (tid<128) h2[tid] = gloadu(ye + t*128 + tid);
    __syncthreads();
    if (Woutp){
      if (tid<128) in2[tid] = pk2(o1f[2*tid]+lo2(h2[tid]), o1f[2*tid+1]+hi2(h2[tid]));
      __syncthreads();
      if (tid<200){
        int so = tid/50;
        float acc=0.f;
        #pragma unroll
        for (int i4=0;i4<8;i4++){
          uint4 uv = ((const uint4*)in2)[so*8+i4];
          acc = fdot2u(uv.x, wo[i4*4+0], acc); acc = fdot2u(uv.y, wo[i4*4+1], acc);
          acc = fdot2u(uv.z, wo[i4*4+2], acc); acc = fdot2u(uv.w, wo[i4*4+3], acc);
        }
        pm[tid]=acc;
      }
      __syncthreads();
      if (tid<50){
        float mel = pm[tid]+pm[50+tid]+pm[100+tid]+pm[150+tid]+bml[tid];
        melout[(size_t)b*80000 + (size_t)t*400 + m*50 + tid] = mel;
      }
      __syncthreads();
    }
  }
}

// ---------- launch ----------
extern "C" void kernel_launch(void* const* d_in, const int* in_sizes, int n_in,
                              void* d_out, int out_size, void* d_ws, size_t ws_size,
                              hipStream_t stream) {
  if (ws_size < WS_NEED) return;
  const float* inputs = (const float*)d_in[0];
  const float* memory = (const float*)d_in[1];
  const float* Wq  = (const float*)d_in[2];
  const float* Wm  = (const float*)d_in[3];
  const float* va  = (const float*)d_in[4];
  const float* Wal = (const float*)d_in[5];
  const float* Wxd = (const float*)d_in[6];
  const float* Whd = (const float*)d_in[7];
  const float* bdec= (const float*)d_in[8];
  const float* Wx1 = (const float*)d_in[9];
  const float* Wh1 = (const float*)d_in[10];
  const float* b1  = (const float*)d_in[11];
  const float* Wx2 = (const float*)d_in[12];
  const float* Wh2 = (const float*)d_in[13];
  const float* b2  = (const float*)d_in[14];
  const float* Wout= (const float*)d_in[15];
  const float* bout= (const float*)d_in[16];
  float* out = (float*)d_out;

  char* wsb = (char*)d_ws;
  unsigned* wsu = (unsigned*)d_ws;
  const unsigned* WXX4 = (const unsigned*)(wsb + OFF_WXX4);
  const unsigned* GW4  = (const unsigned*)(wsb + OFF_GW4);
  const unsigned* QW4  = (const unsigned*)(wsb + OFF_QW4);
  const unsigned* ALW4 = (const unsigned*)(wsb + OFF_ALW4);
  const unsigned* MEM4 = (const unsigned*)(wsb + OFF_MEM4);
  const unsigned* WM4  = (const unsigned*)(wsb + OFF_WM4);
  const unsigned* WX1P = (const unsigned*)(wsb + OFF_WX1P);
  const unsigned* WH1P = (const unsigned*)(wsb + OFF_WH1P);
  const unsigned* WX2P = (const unsigned*)(wsb + OFF_WX2P);
  const unsigned* WH2P = (const unsigned*)(wsb + OFF_WH2P);
  const unsigned* WOUTP= (const unsigned*)(wsb + OFF_WOUTP);
  __half* KEYS = (__half*)(wsb + OFF_KEYS);
  __half* XG   = (__half*)(wsb + OFF_XG);
  unsigned* ATTN2 = (unsigned*)(wsb + OFF_ATTN);
  float* HBUF = (float*)(wsb + OFF_HBUF);
  float* QPART= (float*)(wsb + OFF_QPART);
  float* SCB  = (float*)(wsb + OFF_SCB);
  float* APART= (float*)(wsb + OFF_APART);
  unsigned* Y1u = (unsigned*)(wsb + OFF_Y1);
  unsigned* Y2u = (unsigned*)(wsb + OFF_Y2);
  unsigned* CNT = (unsigned*)wsb;          // 3 x 32 x 8 x 128B flags

  (void)hipMemsetAsync(d_ws, 0, 98304, stream);
  pack_kernel<<<7712, 256, 0, stream>>>(Wxd, Whd, Wq, Wal, Wm, Wx1, Wh1, Wx2, Wh2, Wout, memory, wsu);
  keys_kernel<<<256, 256, 0, stream>>>(memory, WM4, KEYS);
  xg_kernel<<<256, 768, 0, stream>>>(inputs, bdec, WXX4, XG);
  decoder_kernel<<<256, 512, 0, stream>>>(va, GW4, QW4, ALW4, MEM4, (const unsigned*)KEYS, XG,
                                          ATTN2, out, CNT, HBUF, QPART, SCB, APART);
  gru_kernel<<<256, 256, 0, stream>>>(ATTN2, nullptr, WX1P, WH1P, b1, Y1u, CNT + 32*8*FSTRIDE, nullptr, nullptr, nullptr);
  gru_kernel<<<256, 256, 0, stream>>>(ATTN2, Y1u,     WX2P, WH2P, b2, Y2u, CNT + 64*8*FSTRIDE, WOUTP, bout, out);
}